// Round 9
// baseline (842.581 us; speedup 1.0000x reference)
//
#include <hip/hip_runtime.h>
#include <math.h>

// Problem constants (from reference)
constexpr int D = 64;
constexpr int NU = 50000, NB = 20000, NI = 100000;
constexpr int BATCH = 2048, NCAND = 2, MAXDEG = 50, CORE_K = 3;
constexpr int PAD_IDX = NI;
constexpr int N_UB = NU + NB, N_UI = NU + NI, N_BI = NB + NI;
constexpr int N_TOT = N_UB + N_UI + N_BI;   // 340000 combined node space
constexpr int OFF1 = N_UB;                  // UI node base
constexpr int OFF2 = N_UB + N_UI;           // BI node base
constexpr int SCAN_TILE = 1024;             // elems per scan block (256 thr x 4)

__device__ __forceinline__ float wave_sum64(float v) {
#pragma unroll
    for (int off = 32; off > 0; off >>= 1) v += __shfl_down(v, off);
    return v;  // valid in lane 0
}

// NOTE: function, not macro — a macro param named `x` would capture the `.x`
// member token in the body (R4 compile failure).
__device__ __forceinline__ void fma4(float4& a, float v, const float4& u) {
    a.x = fmaf(v, u.x, a.x); a.y = fmaf(v, u.y, a.y);
    a.z = fmaf(v, u.z, a.z); a.w = fmaf(v, u.w, a.w);
}

// ---------------- fused CSR build over combined node space ----------------

__global__ void k_hist3(const int* __restrict__ r0, const int* __restrict__ r1,
                        const int* __restrict__ r2, int e0, int e1, int e2,
                        int* __restrict__ cnt) {
    int i = blockIdx.x * blockDim.x + threadIdx.x;
    if (i >= e0 + e1 + e2) return;
    int r;
    if (i < e0) r = r0[i];
    else if (i < e0 + e1) r = r1[i - e0] + OFF1;
    else r = r2[i - e0 - e1] + OFF2;
    atomicAdd(&cnt[r], 1);
}

// per-block partial sums of cnt tiles (tile = 1024, thread t owns 4 contiguous)
__global__ __launch_bounds__(256) void k_scan1(const int* __restrict__ cnt, int N,
                                               int* __restrict__ bsum) {
    __shared__ int red[256];
    int base = blockIdx.x * SCAN_TILE + threadIdx.x * 4;
    int s = 0;
#pragma unroll
    for (int k = 0; k < 4; ++k) { int i = base + k; if (i < N) s += cnt[i]; }
    red[threadIdx.x] = s;
    __syncthreads();
    for (int w = 128; w > 0; w >>= 1) {
        if (threadIdx.x < w) red[threadIdx.x] += red[threadIdx.x + w];
        __syncthreads();
    }
    if (threadIdx.x == 0) bsum[blockIdx.x] = red[0];
}

// single-block parallel exclusive scan of block sums (nb <= 512), using the
// same double-barrier Hillis-Steele LDS pattern proven in k_scan3 since R3.
// (R7's serial 1-thread version cost ~70us: 333 dependent global round trips.)
// Also writes rs[N] = total.
__global__ __launch_bounds__(256) void k_scan2(int* __restrict__ bsum, int nb,
                                               int* __restrict__ rs_total) {
    __shared__ int s[256];
    int t = threadIdx.x;
    int i0 = 2 * t, i1 = 2 * t + 1;
    int v0 = (i0 < nb) ? bsum[i0] : 0;
    int v1 = (i1 < nb) ? bsum[i1] : 0;
    int ts = v0 + v1;
    s[t] = ts;
    __syncthreads();
    for (int off = 1; off < 256; off <<= 1) {
        int add = (t >= off) ? s[t - off] : 0;
        __syncthreads();
        s[t] += add;
        __syncthreads();
    }
    int pre = s[t] - ts;   // exclusive prefix of this thread's pair
    if (i0 < nb) bsum[i0] = pre;
    if (i1 < nb) bsum[i1] = pre + v0;
    if (t == 255) *rs_total = s[255];   // == E_tot
}

// per-block exclusive scan of tile, + scanned block offset -> row_start & cursor
__global__ __launch_bounds__(256) void k_scan3(const int* __restrict__ cnt, int N,
                                               const int* __restrict__ bsum,
                                               int* __restrict__ rs,
                                               int* __restrict__ cursor) {
    __shared__ int s_ts[256];
    int t = threadIdx.x;
    int base = blockIdx.x * SCAN_TILE + t * 4;
    int v[4];
#pragma unroll
    for (int k = 0; k < 4; ++k) { int i = base + k; v[k] = (i < N) ? cnt[i] : 0; }
    int ts = v[0] + v[1] + v[2] + v[3];
    s_ts[t] = ts;
    __syncthreads();
    for (int off = 1; off < 256; off <<= 1) {
        int add = (t >= off) ? s_ts[t - off] : 0;
        __syncthreads();
        s_ts[t] += add;
        __syncthreads();
    }
    int pre = bsum[blockIdx.x] + (s_ts[t] - ts);
#pragma unroll
    for (int k = 0; k < 4; ++k) {
        int i = base + k;
        if (i < N) { rs[i] = pre; cursor[i] = pre; }
        pre += v[k];
    }
}

// scatter all three edge lists; (col,val) packed into one 8B word, stored with
// a nontemporal hint via a scalar u64 alias (NT builtin rejects HIP_vector_type
// pointers — R8 compile failure). Memory image == int2{col, val_bits}
// (little-endian: col in low 32 bits). cols stored GRAPH-LOCAL.
__global__ void k_scatter3(const int* __restrict__ r0, const int* __restrict__ c0,
                           const float* __restrict__ v0,
                           const int* __restrict__ r1, const int* __restrict__ c1,
                           const float* __restrict__ v1,
                           const int* __restrict__ r2, const int* __restrict__ c2,
                           const float* __restrict__ v2,
                           int e0, int e1, int e2,
                           int* __restrict__ cursor,
                           unsigned long long* __restrict__ cv_s) {
    int i = blockIdx.x * blockDim.x + threadIdx.x;
    if (i >= e0 + e1 + e2) return;
    int r, c; float v;
    if (i < e0)            { r = r0[i];          c = c0[i];          v = v0[i]; }
    else if (i < e0 + e1)  { int k = i - e0;      r = r1[k] + OFF1;   c = c1[k]; v = v1[k]; }
    else                   { int k = i - e0 - e1; r = r2[k] + OFF2;   c = c2[k]; v = v2[k]; }
    int p = atomicAdd(&cursor[r], 1);
    unsigned long long packed = (unsigned long long)(unsigned int)c |
                                ((unsigned long long)(unsigned int)__float_as_uint(v) << 32);
    __builtin_nontemporal_store(packed, &cv_s[p]);
}

// ---------------- propagate (CSR gather, 16 lanes x float4 per row) --------

// layer 1: y1[r] = sum_j val[j] * f[col[j]]  where f = concat(fa, fb), cols local
__global__ __launch_bounds__(256) void k_spmm_l1(
    const int* __restrict__ rs, const int2* __restrict__ cv,
    const float* __restrict__ fa, const float* __restrict__ fb, int na,
    float* __restrict__ y1, int N) {
    int r = blockIdx.x * 16 + (threadIdx.x >> 4);
    int t = threadIdx.x & 15;
    if (r >= N) return;
    int s = rs[r], e = rs[r + 1];
    float4 a0 = {0,0,0,0}, a1 = {0,0,0,0}, a2 = {0,0,0,0}, a3 = {0,0,0,0};
    int j = s;
    for (; j + 3 < e; j += 4) {
        int2 q0 = cv[j], q1 = cv[j+1], q2 = cv[j+2], q3 = cv[j+3];
        int c0 = q0.x, c1 = q1.x, c2 = q2.x, c3 = q3.x;
        float v0 = __int_as_float(q0.y), v1 = __int_as_float(q1.y);
        float v2 = __int_as_float(q2.y), v3 = __int_as_float(q3.y);
        const float* p0 = (c0 < na) ? fa + (size_t)c0 * D : fb + (size_t)(c0 - na) * D;
        const float* p1 = (c1 < na) ? fa + (size_t)c1 * D : fb + (size_t)(c1 - na) * D;
        const float* p2 = (c2 < na) ? fa + (size_t)c2 * D : fb + (size_t)(c2 - na) * D;
        const float* p3 = (c3 < na) ? fa + (size_t)c3 * D : fb + (size_t)(c3 - na) * D;
        float4 x0 = *(const float4*)(p0 + t * 4);
        float4 x1 = *(const float4*)(p1 + t * 4);
        float4 x2 = *(const float4*)(p2 + t * 4);
        float4 x3 = *(const float4*)(p3 + t * 4);
        fma4(a0, v0, x0); fma4(a1, v1, x1); fma4(a2, v2, x2); fma4(a3, v3, x3);
    }
    for (; j < e; ++j) {
        int2 q0 = cv[j];
        int c0 = q0.x;
        float v0 = __int_as_float(q0.y);
        const float* p0 = (c0 < na) ? fa + (size_t)c0 * D : fb + (size_t)(c0 - na) * D;
        float4 x0 = *(const float4*)(p0 + t * 4);
        fma4(a0, v0, x0);
    }
    a0.x += a1.x + a2.x + a3.x; a0.y += a1.y + a2.y + a3.y;
    a0.z += a1.z + a2.z + a3.z; a0.w += a1.w + a2.w + a3.w;
    *(float4*)(y1 + (size_t)r * D + t * 4) = a0;
}

// layer 2 fused with mean: acc[r] = (f[r] + y1[r] + sum_j val[j]*y1[col[j]]) / 3
__global__ __launch_bounds__(256) void k_spmm_l2(
    const int* __restrict__ rs, const int2* __restrict__ cv,
    const float* __restrict__ y1,
    const float* __restrict__ fa, const float* __restrict__ fb, int na,
    float* __restrict__ acc, int N) {
    int r = blockIdx.x * 16 + (threadIdx.x >> 4);
    int t = threadIdx.x & 15;
    if (r >= N) return;
    int s = rs[r], e = rs[r + 1];
    float4 a0 = {0,0,0,0}, a1 = {0,0,0,0}, a2 = {0,0,0,0}, a3 = {0,0,0,0};
    int j = s;
    for (; j + 3 < e; j += 4) {
        int2 q0 = cv[j], q1 = cv[j+1], q2 = cv[j+2], q3 = cv[j+3];
        float v0 = __int_as_float(q0.y), v1 = __int_as_float(q1.y);
        float v2 = __int_as_float(q2.y), v3 = __int_as_float(q3.y);
        float4 x0 = *(const float4*)(y1 + (size_t)q0.x * D + t * 4);
        float4 x1 = *(const float4*)(y1 + (size_t)q1.x * D + t * 4);
        float4 x2 = *(const float4*)(y1 + (size_t)q2.x * D + t * 4);
        float4 x3 = *(const float4*)(y1 + (size_t)q3.x * D + t * 4);
        fma4(a0, v0, x0); fma4(a1, v1, x1); fma4(a2, v2, x2); fma4(a3, v3, x3);
    }
    for (; j < e; ++j) {
        int2 q0 = cv[j];
        float v0 = __int_as_float(q0.y);
        float4 x0 = *(const float4*)(y1 + (size_t)q0.x * D + t * 4);
        fma4(a0, v0, x0);
    }
    const float* pf = (r < na) ? fa + (size_t)r * D : fb + (size_t)(r - na) * D;
    float4 f0 = *(const float4*)(pf + t * 4);
    float4 yv = *(const float4*)(y1 + (size_t)r * D + t * 4);
    constexpr float k3 = 1.0f / 3.0f;
    float4 o;
    o.x = (f0.x + yv.x + a0.x + a1.x + a2.x + a3.x) * k3;
    o.y = (f0.y + yv.y + a0.y + a1.y + a2.y + a3.y) * k3;
    o.z = (f0.z + yv.z + a0.z + a1.z + a2.z + a3.z) * k3;
    o.w = (f0.w + yv.w + a0.w + a1.w + a2.w + a3.w) * k3;
    *(float4*)(acc + (size_t)r * D + t * 4) = o;
}

// ---------------- scoring ----------------
// 256-thread block per candidate pair. CONSERVATIVE phase structure: every
// cross-phase value goes through LDS + __syncthreads(); softmax+top-k is
// R3's proven serial thread-0 code. No same-wave LDS RAW anywhere.
__global__ __launch_bounds__(256) void k_score(
    const int* __restrict__ users, const int* __restrict__ bundles,
    const int* __restrict__ bundle_items,
    const float* __restrict__ m_ub, const float* __restrict__ m_ui,
    const float* __restrict__ m_bi,
    const float* __restrict__ cw1, const float* __restrict__ cb1,
    const float* __restrict__ cw2, const float* __restrict__ cb2,
    const float* __restrict__ sw1, const float* __restrict__ sb1,
    const float* __restrict__ sw2, const float* __restrict__ sb2,
    float* __restrict__ scores) {
    const int n = blockIdx.x;
    const int t = threadIdx.x;      // 0..255
    const int ln = t & 63;          // lane within wave
    const int wv = t >> 6;          // wave 0..3
    const int g16 = t >> 4;         // group 0..15
    const int l16 = t & 15;         // lane within group
    const int u = users[n >> 1];
    const int b = bundles[n];

    __shared__ float s_items[MAXDEG][D];   // items_ui stash (12.8 KB)
    __shared__ float s_r[2][MAXDEG];
    __shared__ float s_pi[MAXDEG];
    __shared__ int   s_idx[MAXDEG];
    __shared__ int   s_top_i[CORE_K];
    __shared__ float s_top_p[CORE_K];
    __shared__ float s_syn[2 * D];
    __shared__ float s_part[4][D];
    __shared__ float s_h1[D];

    if (t < MAXDEG) s_idx[t] = bundle_items[(size_t)b * MAXDEG + t];
    __syncthreads();

    // this thread's 4-feature segment of the u / b rows
    const float4 u4 = *(const float4*)(m_ui + (size_t)u * D + l16 * 4);
    const float4 b4 = *(const float4*)(m_bi + (size_t)b * D + l16 * 4);

    // --- P1: 50 dual dot products, 16 items in flight (16 lanes x float4) ---
    for (int m = g16; m < MAXDEG; m += 16) {
        int it = s_idx[m];
        float4 iu = {0,0,0,0}, ib = {0,0,0,0};
        if (it != PAD_IDX) {
            iu = *(const float4*)(m_ui + (size_t)(NU + it) * D + l16 * 4);
            ib = *(const float4*)(m_bi + (size_t)(NB + it) * D + l16 * 4);
        }
        *(float4*)(&s_items[m][l16 * 4]) = iu;
        float pu = u4.x*iu.x + u4.y*iu.y + u4.z*iu.z + u4.w*iu.w;
        float pb = b4.x*ib.x + b4.y*ib.y + b4.z*ib.z + b4.w*ib.w;
#pragma unroll
        for (int off = 8; off > 0; off >>= 1) {
            pu += __shfl_down(pu, off, 16);
            pb += __shfl_down(pb, off, 16);
        }
        if (l16 == 0) { s_r[0][m] = pu; s_r[1][m] = pb; }
    }
    __syncthreads();

    // --- P2: core MLP (2->32->1) per item, threads 0..49; logits -> s_pi ---
    if (t < MAXDEG) {
        float rU = s_r[0][t], rB = s_r[1][t];
        float acc = cb2[0];
#pragma unroll
        for (int j = 0; j < 32; ++j) {
            float h = fmaf(rU, cw1[j], fmaf(rB, cw1[32 + j], cb1[j]));
            h = fmaxf(h, 0.f);
            acc = fmaf(h, cw2[j], acc);
        }
        s_pi[t] = (s_idx[t] != PAD_IDX) ? acc : -INFINITY;
    }
    __syncthreads();

    // --- P3 (thread 0, serial; R3-proven): softmax + top-3 ---
    if (t == 0) {
        float mx = -INFINITY;
        for (int m = 0; m < MAXDEG; ++m) mx = fmaxf(mx, s_pi[m]);
        float sm = 0.f;
        for (int m = 0; m < MAXDEG; ++m) {
            float e = expf(s_pi[m] - mx);
            s_pi[m] = e;
            sm += e;
        }
        float inv_sm = 1.f / sm;
        for (int m = 0; m < MAXDEG; ++m) s_pi[m] *= inv_sm;
        bool used[MAXDEG];
        for (int m = 0; m < MAXDEG; ++m) used[m] = false;
        float tsum = 0.f;
        for (int k = 0; k < CORE_K; ++k) {
            float best = -1.f; int bidx = 0;
            for (int m = 0; m < MAXDEG; ++m)
                if (!used[m] && s_pi[m] > best) { best = s_pi[m]; bidx = m; }
            used[bidx] = true;
            s_top_i[k] = bidx;
            s_top_p[k] = best;
            tsum += best;
        }
        float inv = 1.f / (tsum + 1e-10f);
        for (int k = 0; k < CORE_K; ++k) s_top_p[k] *= inv;
    }
    __syncthreads();

    // --- P4 (wave 0): h_core / h_fringe per feature dim ln ---
    if (wv == 0) {
        int ti0 = s_top_i[0], ti1 = s_top_i[1], ti2 = s_top_i[2];
        float hcore = s_items[ti0][ln] * s_top_p[0]
                    + s_items[ti1][ln] * s_top_p[1]
                    + s_items[ti2][ln] * s_top_p[2];
        float fsum = 0.f; int fcnt = 0;
        for (int m = 0; m < MAXDEG; ++m) {
            bool core = (m == ti0) | (m == ti1) | (m == ti2);
            if ((s_idx[m] != PAD_IDX) && !core) { fsum += s_items[m][ln]; fcnt++; }
        }
        float hfr = fsum / fmaxf((float)fcnt, 1.f);
        s_syn[ln] = hcore;
        s_syn[D + ln] = hfr;
    }
    __syncthreads();

    // --- P5: synergy MLP (128->64->64) split across 4 waves ---
    float h1p = 0.f;
    for (int k = 0; k < 32; ++k) {
        int kk = wv * 32 + k;
        h1p = fmaf(s_syn[kk], sw1[kk * D + ln], h1p);
    }
    s_part[wv][ln] = h1p;
    __syncthreads();
    if (t < D) {
        float h1 = sb1[t] + s_part[0][t] + s_part[1][t] + s_part[2][t] + s_part[3][t];
        s_h1[t] = fmaxf(h1, 0.f);
    }
    __syncthreads();
    float php = 0.f;
    for (int k = 0; k < 16; ++k) {
        int kk = wv * 16 + k;
        php = fmaf(s_h1[kk], sw2[kk * D + ln], php);
    }
    s_part[wv][ln] = php;
    __syncthreads();

    // --- P6 (wave 0): final score ---
    if (wv == 0) {
        float phi = sb2[ln] + s_part[0][ln] + s_part[1][ln] + s_part[2][ln] + s_part[3][ln];
        float hat = s_syn[ln] + phi;     // hcore + phi
        float uui = m_ui[(size_t)u * D + ln];
        float ubu = m_ub[(size_t)u * D + ln];
        float ubb = m_ub[(size_t)(NU + b) * D + ln];
        float part = wave_sum64(uui * ubb + ubu * hat);
        if (ln == 0) scores[n] = part;
    }
}

// mean over batch of softplus(neg - pos)
__global__ __launch_bounds__(256) void k_loss(const float* __restrict__ scores,
                                              float* __restrict__ out) {
    __shared__ float red[256];
    float s = 0.f;
    for (int i = threadIdx.x; i < BATCH; i += 256) {
        float x = scores[i * 2 + 1] - scores[i * 2 + 0];
        s += fmaxf(x, 0.f) + log1pf(expf(-fabsf(x)));
    }
    red[threadIdx.x] = s;
    __syncthreads();
    for (int w = 128; w > 0; w >>= 1) {
        if (threadIdx.x < w) red[threadIdx.x] += red[threadIdx.x + w];
        __syncthreads();
    }
    if (threadIdx.x == 0) out[0] = red[0] / (float)BATCH;
}

extern "C" void kernel_launch(void* const* d_in, const int* in_sizes, int n_in,
                              void* d_out, int out_size, void* d_ws, size_t ws_size,
                              hipStream_t stream) {
    const float* users_feature   = (const float*)d_in[0];
    const float* bundles_feature = (const float*)d_in[1];
    const float* items_feature   = (const float*)d_in[2];
    const float* cw1 = (const float*)d_in[3];
    const float* cb1 = (const float*)d_in[4];
    const float* cw2 = (const float*)d_in[5];
    const float* cb2 = (const float*)d_in[6];
    const float* sw1 = (const float*)d_in[7];
    const float* sb1 = (const float*)d_in[8];
    const float* sw2 = (const float*)d_in[9];
    const float* sb2 = (const float*)d_in[10];
    const float* ub_val = (const float*)d_in[11];
    const float* ui_val = (const float*)d_in[12];
    const float* bi_val = (const float*)d_in[13];
    const int* users   = (const int*)d_in[14];
    const int* bundles = (const int*)d_in[15];
    const int* ub_row = (const int*)d_in[16];
    const int* ub_col = (const int*)d_in[17];
    const int* ui_row = (const int*)d_in[18];
    const int* ui_col = (const int*)d_in[19];
    const int* bi_row = (const int*)d_in[20];
    const int* bi_col = (const int*)d_in[21];
    const int* bundle_items = (const int*)d_in[22];
    const int E_UB = in_sizes[11], E_UI = in_sizes[12], E_BI = in_sizes[13];
    const int E_TOT = E_UB + E_UI + E_BI;

    // workspace layout (4-byte elements), ~154 MB total.
    // cv_s (8B words) must be 8B-aligned: all preceding sizes kept even.
    float* ws = (float*)d_ws;
    size_t off = 0;
    float* acc    = ws + off; off += (size_t)N_TOT * D;   // combined reps, 87 MB
    float* y1buf  = ws + off; off += (size_t)N_UI * D;    // per-graph temp, 38.4 MB
    float* scores = ws + off; off += (size_t)BATCH * NCAND;
    int*   cnt    = (int*)(ws + off); off += N_TOT;
    int*   rstart = (int*)(ws + off); off += N_TOT + 2;   // +2 keeps 8B alignment
    int*   cursor = (int*)(ws + off); off += N_TOT;
    int*   bsum   = (int*)(ws + off); off += 512;
    unsigned long long* cv_s = (unsigned long long*)(ws + off);
    off += (size_t)E_TOT * 2;                             // packed (col,val)
    if (ws_size < off * sizeof(float)) return;  // fail loudly (wrong answer)

    // ---- fused CSR build (once, combined 340K-node space) ----
    hipMemsetAsync(cnt, 0, (size_t)N_TOT * sizeof(int), stream);
    k_hist3<<<(E_TOT + 255) / 256, 256, 0, stream>>>(ub_row, ui_row, bi_row,
                                                     E_UB, E_UI, E_BI, cnt);
    int nb = (N_TOT + SCAN_TILE - 1) / SCAN_TILE;   // 333
    k_scan1<<<nb, 256, 0, stream>>>(cnt, N_TOT, bsum);
    k_scan2<<<1, 256, 0, stream>>>(bsum, nb, rstart + N_TOT);
    k_scan3<<<nb, 256, 0, stream>>>(cnt, N_TOT, bsum, rstart, cursor);
    k_scatter3<<<(E_TOT + 255) / 256, 256, 0, stream>>>(
        ub_row, ub_col, ub_val, ui_row, ui_col, ui_val, bi_row, bi_col, bi_val,
        E_UB, E_UI, E_BI, cursor, cv_s);

    // ---- per-graph propagation (rs offsets index the combined edge array) --
    const int2* cv_i2 = (const int2*)cv_s;   // same memory image, int2 view
    auto propagate = [&](int row_off, int n, const float* fa, int na,
                         const float* fb) {
        const int* rs = rstart + row_off;
        float* accg = acc + (size_t)row_off * D;
        int sb = (n + 15) / 16;
        k_spmm_l1<<<sb, 256, 0, stream>>>(rs, cv_i2, fa, fb, na, y1buf, n);
        k_spmm_l2<<<sb, 256, 0, stream>>>(rs, cv_i2, y1buf, fa, fb, na, accg, n);
    };
    propagate(0,    N_UB, users_feature,   NU, bundles_feature);
    propagate(OFF1, N_UI, users_feature,   NU, items_feature);
    propagate(OFF2, N_BI, bundles_feature, NB, items_feature);

    k_score<<<BATCH * NCAND, 256, 0, stream>>>(
        users, bundles, bundle_items,
        acc, acc + (size_t)OFF1 * D, acc + (size_t)OFF2 * D,
        cw1, cb1, cw2, cb2, sw1, sb1, sw2, sb2, scores);

    k_loss<<<1, 256, 0, stream>>>(scores, (float*)d_out);
}

// Round 10
// 774.110 us; speedup vs baseline: 1.0885x; 1.0885x over previous
//
#include <hip/hip_runtime.h>
#include <math.h>

// Problem constants (from reference)
constexpr int D = 64;
constexpr int NU = 50000, NB = 20000, NI = 100000;
constexpr int BATCH = 2048, NCAND = 2, MAXDEG = 50, CORE_K = 3;
constexpr int PAD_IDX = NI;
constexpr int N_UB = NU + NB, N_UI = NU + NI, N_BI = NB + NI;
constexpr int N_TOT = N_UB + N_UI + N_BI;   // 340000 combined node space
constexpr int OFF1 = N_UB;                  // UI node base
constexpr int OFF2 = N_UB + N_UI;           // BI node base
constexpr int SCAN_TILE = 1024;             // elems per scan block (256 thr x 4)

__device__ __forceinline__ float wave_sum64(float v) {
#pragma unroll
    for (int off = 32; off > 0; off >>= 1) v += __shfl_down(v, off);
    return v;  // valid in lane 0
}

// NOTE: function, not macro — a macro param named `x` would capture the `.x`
// member token in the body (R4 compile failure).
__device__ __forceinline__ void fma4(float4& a, float v, const float4& u) {
    a.x = fmaf(v, u.x, a.x); a.y = fmaf(v, u.y, a.y);
    a.z = fmaf(v, u.z, a.z); a.w = fmaf(v, u.w, a.w);
}

// ---------------- fused CSR build over combined node space ----------------

__global__ void k_hist3(const int* __restrict__ r0, const int* __restrict__ r1,
                        const int* __restrict__ r2, int e0, int e1, int e2,
                        int* __restrict__ cnt) {
    int i = blockIdx.x * blockDim.x + threadIdx.x;
    if (i >= e0 + e1 + e2) return;
    int r;
    if (i < e0) r = r0[i];
    else if (i < e0 + e1) r = r1[i - e0] + OFF1;
    else r = r2[i - e0 - e1] + OFF2;
    atomicAdd(&cnt[r], 1);
}

// per-block partial sums of cnt tiles (tile = 1024, thread t owns 4 contiguous)
__global__ __launch_bounds__(256) void k_scan1(const int* __restrict__ cnt, int N,
                                               int* __restrict__ bsum) {
    __shared__ int red[256];
    int base = blockIdx.x * SCAN_TILE + threadIdx.x * 4;
    int s = 0;
#pragma unroll
    for (int k = 0; k < 4; ++k) { int i = base + k; if (i < N) s += cnt[i]; }
    red[threadIdx.x] = s;
    __syncthreads();
    for (int w = 128; w > 0; w >>= 1) {
        if (threadIdx.x < w) red[threadIdx.x] += red[threadIdx.x + w];
        __syncthreads();
    }
    if (threadIdx.x == 0) bsum[blockIdx.x] = red[0];
}

// single-block parallel exclusive scan of block sums (nb <= 512), double-barrier
// Hillis-Steele (proven R9; R7's serial version cost ~25-70us).
// Also writes rs[N] = total.
__global__ __launch_bounds__(256) void k_scan2(int* __restrict__ bsum, int nb,
                                               int* __restrict__ rs_total) {
    __shared__ int s[256];
    int t = threadIdx.x;
    int i0 = 2 * t, i1 = 2 * t + 1;
    int v0 = (i0 < nb) ? bsum[i0] : 0;
    int v1 = (i1 < nb) ? bsum[i1] : 0;
    int ts = v0 + v1;
    s[t] = ts;
    __syncthreads();
    for (int off = 1; off < 256; off <<= 1) {
        int add = (t >= off) ? s[t - off] : 0;
        __syncthreads();
        s[t] += add;
        __syncthreads();
    }
    int pre = s[t] - ts;   // exclusive prefix of this thread's pair
    if (i0 < nb) bsum[i0] = pre;
    if (i1 < nb) bsum[i1] = pre + v0;
    if (t == 255) *rs_total = s[255];   // == E_tot
}

// per-block exclusive scan of tile, + scanned block offset -> row_start & cursor
__global__ __launch_bounds__(256) void k_scan3(const int* __restrict__ cnt, int N,
                                               const int* __restrict__ bsum,
                                               int* __restrict__ rs,
                                               int* __restrict__ cursor) {
    __shared__ int s_ts[256];
    int t = threadIdx.x;
    int base = blockIdx.x * SCAN_TILE + t * 4;
    int v[4];
#pragma unroll
    for (int k = 0; k < 4; ++k) { int i = base + k; v[k] = (i < N) ? cnt[i] : 0; }
    int ts = v[0] + v[1] + v[2] + v[3];
    s_ts[t] = ts;
    __syncthreads();
    for (int off = 1; off < 256; off <<= 1) {
        int add = (t >= off) ? s_ts[t - off] : 0;
        __syncthreads();
        s_ts[t] += add;
        __syncthreads();
    }
    int pre = bsum[blockIdx.x] + (s_ts[t] - ts);
#pragma unroll
    for (int k = 0; k < 4; ++k) {
        int i = base + k;
        if (i < N) { rs[i] = pre; cursor[i] = pre; }
        pre += v[k];
    }
}

// scatter all three edge lists; (col,val) packed into one int2 -> single 8B
// PLAIN store (R9 post-mortem: nontemporal hint bypasses L2 write-combining
// and cost +70us on scattered partial-line writes — keep L2 in the path).
// cols stored GRAPH-LOCAL.
__global__ void k_scatter3(const int* __restrict__ r0, const int* __restrict__ c0,
                           const float* __restrict__ v0,
                           const int* __restrict__ r1, const int* __restrict__ c1,
                           const float* __restrict__ v1,
                           const int* __restrict__ r2, const int* __restrict__ c2,
                           const float* __restrict__ v2,
                           int e0, int e1, int e2,
                           int* __restrict__ cursor,
                           int2* __restrict__ cv_s) {
    int i = blockIdx.x * blockDim.x + threadIdx.x;
    if (i >= e0 + e1 + e2) return;
    int r, c; float v;
    if (i < e0)            { r = r0[i];          c = c0[i];          v = v0[i]; }
    else if (i < e0 + e1)  { int k = i - e0;      r = r1[k] + OFF1;   c = c1[k]; v = v1[k]; }
    else                   { int k = i - e0 - e1; r = r2[k] + OFF2;   c = c2[k]; v = v2[k]; }
    int p = atomicAdd(&cursor[r], 1);
    cv_s[p] = make_int2(c, __float_as_int(v));
}

// ---------------- propagate (CSR gather, 16 lanes x float4 per row) --------
// Unroll 8 (R10): avg degree ~9, so one 8-wide iteration covers most of a row
// with 8 gathers in flight per group (was 4). Batched loads -> FMAs.

__device__ __forceinline__ const float* row_ptr(int c, const float* fa,
                                                const float* fb, int na) {
    return (c < na) ? fa + (size_t)c * D : fb + (size_t)(c - na) * D;
}

// layer 1: y1[r] = sum_j val[j] * f[col[j]]  where f = concat(fa, fb), cols local
__global__ __launch_bounds__(256) void k_spmm_l1(
    const int* __restrict__ rs, const int2* __restrict__ cv,
    const float* __restrict__ fa, const float* __restrict__ fb, int na,
    float* __restrict__ y1, int N) {
    int r = blockIdx.x * 16 + (threadIdx.x >> 4);
    int t = threadIdx.x & 15;
    if (r >= N) return;
    int s = rs[r], e = rs[r + 1];
    float4 a[4];
#pragma unroll
    for (int k = 0; k < 4; ++k) a[k] = make_float4(0.f, 0.f, 0.f, 0.f);
    int j = s;
    for (; j + 7 < e; j += 8) {
        int2 q[8];
#pragma unroll
        for (int k = 0; k < 8; ++k) q[k] = cv[j + k];
        float4 xv[8];
#pragma unroll
        for (int k = 0; k < 8; ++k)
            xv[k] = *(const float4*)(row_ptr(q[k].x, fa, fb, na) + t * 4);
#pragma unroll
        for (int k = 0; k < 8; ++k)
            fma4(a[k & 3], __int_as_float(q[k].y), xv[k]);
    }
    for (; j + 3 < e; j += 4) {
        int2 q[4];
#pragma unroll
        for (int k = 0; k < 4; ++k) q[k] = cv[j + k];
        float4 xv[4];
#pragma unroll
        for (int k = 0; k < 4; ++k)
            xv[k] = *(const float4*)(row_ptr(q[k].x, fa, fb, na) + t * 4);
#pragma unroll
        for (int k = 0; k < 4; ++k)
            fma4(a[k], __int_as_float(q[k].y), xv[k]);
    }
    for (; j < e; ++j) {
        int2 q0 = cv[j];
        float4 x0 = *(const float4*)(row_ptr(q0.x, fa, fb, na) + t * 4);
        fma4(a[0], __int_as_float(q0.y), x0);
    }
    float4 o;
    o.x = a[0].x + a[1].x + a[2].x + a[3].x;
    o.y = a[0].y + a[1].y + a[2].y + a[3].y;
    o.z = a[0].z + a[1].z + a[2].z + a[3].z;
    o.w = a[0].w + a[1].w + a[2].w + a[3].w;
    *(float4*)(y1 + (size_t)r * D + t * 4) = o;
}

// layer 2 fused with mean: acc[r] = (f[r] + y1[r] + sum_j val[j]*y1[col[j]]) / 3
__global__ __launch_bounds__(256) void k_spmm_l2(
    const int* __restrict__ rs, const int2* __restrict__ cv,
    const float* __restrict__ y1,
    const float* __restrict__ fa, const float* __restrict__ fb, int na,
    float* __restrict__ acc, int N) {
    int r = blockIdx.x * 16 + (threadIdx.x >> 4);
    int t = threadIdx.x & 15;
    if (r >= N) return;
    int s = rs[r], e = rs[r + 1];
    float4 a[4];
#pragma unroll
    for (int k = 0; k < 4; ++k) a[k] = make_float4(0.f, 0.f, 0.f, 0.f);
    int j = s;
    for (; j + 7 < e; j += 8) {
        int2 q[8];
#pragma unroll
        for (int k = 0; k < 8; ++k) q[k] = cv[j + k];
        float4 xv[8];
#pragma unroll
        for (int k = 0; k < 8; ++k)
            xv[k] = *(const float4*)(y1 + (size_t)q[k].x * D + t * 4);
#pragma unroll
        for (int k = 0; k < 8; ++k)
            fma4(a[k & 3], __int_as_float(q[k].y), xv[k]);
    }
    for (; j + 3 < e; j += 4) {
        int2 q[4];
#pragma unroll
        for (int k = 0; k < 4; ++k) q[k] = cv[j + k];
        float4 xv[4];
#pragma unroll
        for (int k = 0; k < 4; ++k)
            xv[k] = *(const float4*)(y1 + (size_t)q[k].x * D + t * 4);
#pragma unroll
        for (int k = 0; k < 4; ++k)
            fma4(a[k], __int_as_float(q[k].y), xv[k]);
    }
    for (; j < e; ++j) {
        int2 q0 = cv[j];
        float4 x0 = *(const float4*)(y1 + (size_t)q0.x * D + t * 4);
        fma4(a[0], __int_as_float(q0.y), x0);
    }
    const float* pf = (r < na) ? fa + (size_t)r * D : fb + (size_t)(r - na) * D;
    float4 f0 = *(const float4*)(pf + t * 4);
    float4 yv = *(const float4*)(y1 + (size_t)r * D + t * 4);
    constexpr float k3 = 1.0f / 3.0f;
    float4 o;
    o.x = (f0.x + yv.x + a[0].x + a[1].x + a[2].x + a[3].x) * k3;
    o.y = (f0.y + yv.y + a[0].y + a[1].y + a[2].y + a[3].y) * k3;
    o.z = (f0.z + yv.z + a[0].z + a[1].z + a[2].z + a[3].z) * k3;
    o.w = (f0.w + yv.w + a[0].w + a[1].w + a[2].w + a[3].w) * k3;
    *(float4*)(acc + (size_t)r * D + t * 4) = o;
}

// ---------------- scoring ----------------
// 256-thread block per candidate pair. CONSERVATIVE phase structure: every
// cross-phase value goes through LDS + __syncthreads(); softmax+top-k is
// R3's proven serial thread-0 code. No same-wave LDS RAW anywhere.
__global__ __launch_bounds__(256) void k_score(
    const int* __restrict__ users, const int* __restrict__ bundles,
    const int* __restrict__ bundle_items,
    const float* __restrict__ m_ub, const float* __restrict__ m_ui,
    const float* __restrict__ m_bi,
    const float* __restrict__ cw1, const float* __restrict__ cb1,
    const float* __restrict__ cw2, const float* __restrict__ cb2,
    const float* __restrict__ sw1, const float* __restrict__ sb1,
    const float* __restrict__ sw2, const float* __restrict__ sb2,
    float* __restrict__ scores) {
    const int n = blockIdx.x;
    const int t = threadIdx.x;      // 0..255
    const int ln = t & 63;          // lane within wave
    const int wv = t >> 6;          // wave 0..3
    const int g16 = t >> 4;         // group 0..15
    const int l16 = t & 15;         // lane within group
    const int u = users[n >> 1];
    const int b = bundles[n];

    __shared__ float s_items[MAXDEG][D];   // items_ui stash (12.8 KB)
    __shared__ float s_r[2][MAXDEG];
    __shared__ float s_pi[MAXDEG];
    __shared__ int   s_idx[MAXDEG];
    __shared__ int   s_top_i[CORE_K];
    __shared__ float s_top_p[CORE_K];
    __shared__ float s_syn[2 * D];
    __shared__ float s_part[4][D];
    __shared__ float s_h1[D];

    if (t < MAXDEG) s_idx[t] = bundle_items[(size_t)b * MAXDEG + t];
    __syncthreads();

    // this thread's 4-feature segment of the u / b rows
    const float4 u4 = *(const float4*)(m_ui + (size_t)u * D + l16 * 4);
    const float4 b4 = *(const float4*)(m_bi + (size_t)b * D + l16 * 4);

    // --- P1: 50 dual dot products, 16 items in flight (16 lanes x float4) ---
    for (int m = g16; m < MAXDEG; m += 16) {
        int it = s_idx[m];
        float4 iu = {0,0,0,0}, ib = {0,0,0,0};
        if (it != PAD_IDX) {
            iu = *(const float4*)(m_ui + (size_t)(NU + it) * D + l16 * 4);
            ib = *(const float4*)(m_bi + (size_t)(NB + it) * D + l16 * 4);
        }
        *(float4*)(&s_items[m][l16 * 4]) = iu;
        float pu = u4.x*iu.x + u4.y*iu.y + u4.z*iu.z + u4.w*iu.w;
        float pb = b4.x*ib.x + b4.y*ib.y + b4.z*ib.z + b4.w*ib.w;
#pragma unroll
        for (int off = 8; off > 0; off >>= 1) {
            pu += __shfl_down(pu, off, 16);
            pb += __shfl_down(pb, off, 16);
        }
        if (l16 == 0) { s_r[0][m] = pu; s_r[1][m] = pb; }
    }
    __syncthreads();

    // --- P2: core MLP (2->32->1) per item, threads 0..49; logits -> s_pi ---
    if (t < MAXDEG) {
        float rU = s_r[0][t], rB = s_r[1][t];
        float acc = cb2[0];
#pragma unroll
        for (int j = 0; j < 32; ++j) {
            float h = fmaf(rU, cw1[j], fmaf(rB, cw1[32 + j], cb1[j]));
            h = fmaxf(h, 0.f);
            acc = fmaf(h, cw2[j], acc);
        }
        s_pi[t] = (s_idx[t] != PAD_IDX) ? acc : -INFINITY;
    }
    __syncthreads();

    // --- P3 (thread 0, serial; R3-proven): softmax + top-3 ---
    if (t == 0) {
        float mx = -INFINITY;
        for (int m = 0; m < MAXDEG; ++m) mx = fmaxf(mx, s_pi[m]);
        float sm = 0.f;
        for (int m = 0; m < MAXDEG; ++m) {
            float e = expf(s_pi[m] - mx);
            s_pi[m] = e;
            sm += e;
        }
        float inv_sm = 1.f / sm;
        for (int m = 0; m < MAXDEG; ++m) s_pi[m] *= inv_sm;
        bool used[MAXDEG];
        for (int m = 0; m < MAXDEG; ++m) used[m] = false;
        float tsum = 0.f;
        for (int k = 0; k < CORE_K; ++k) {
            float best = -1.f; int bidx = 0;
            for (int m = 0; m < MAXDEG; ++m)
                if (!used[m] && s_pi[m] > best) { best = s_pi[m]; bidx = m; }
            used[bidx] = true;
            s_top_i[k] = bidx;
            s_top_p[k] = best;
            tsum += best;
        }
        float inv = 1.f / (tsum + 1e-10f);
        for (int k = 0; k < CORE_K; ++k) s_top_p[k] *= inv;
    }
    __syncthreads();

    // --- P4 (wave 0): h_core / h_fringe per feature dim ln ---
    if (wv == 0) {
        int ti0 = s_top_i[0], ti1 = s_top_i[1], ti2 = s_top_i[2];
        float hcore = s_items[ti0][ln] * s_top_p[0]
                    + s_items[ti1][ln] * s_top_p[1]
                    + s_items[ti2][ln] * s_top_p[2];
        float fsum = 0.f; int fcnt = 0;
        for (int m = 0; m < MAXDEG; ++m) {
            bool core = (m == ti0) | (m == ti1) | (m == ti2);
            if ((s_idx[m] != PAD_IDX) && !core) { fsum += s_items[m][ln]; fcnt++; }
        }
        float hfr = fsum / fmaxf((float)fcnt, 1.f);
        s_syn[ln] = hcore;
        s_syn[D + ln] = hfr;
    }
    __syncthreads();

    // --- P5: synergy MLP (128->64->64) split across 4 waves ---
    float h1p = 0.f;
    for (int k = 0; k < 32; ++k) {
        int kk = wv * 32 + k;
        h1p = fmaf(s_syn[kk], sw1[kk * D + ln], h1p);
    }
    s_part[wv][ln] = h1p;
    __syncthreads();
    if (t < D) {
        float h1 = sb1[t] + s_part[0][t] + s_part[1][t] + s_part[2][t] + s_part[3][t];
        s_h1[t] = fmaxf(h1, 0.f);
    }
    __syncthreads();
    float php = 0.f;
    for (int k = 0; k < 16; ++k) {
        int kk = wv * 16 + k;
        php = fmaf(s_h1[kk], sw2[kk * D + ln], php);
    }
    s_part[wv][ln] = php;
    __syncthreads();

    // --- P6 (wave 0): final score ---
    if (wv == 0) {
        float phi = sb2[ln] + s_part[0][ln] + s_part[1][ln] + s_part[2][ln] + s_part[3][ln];
        float hat = s_syn[ln] + phi;     // hcore + phi
        float uui = m_ui[(size_t)u * D + ln];
        float ubu = m_ub[(size_t)u * D + ln];
        float ubb = m_ub[(size_t)(NU + b) * D + ln];
        float part = wave_sum64(uui * ubb + ubu * hat);
        if (ln == 0) scores[n] = part;
    }
}

// mean over batch of softplus(neg - pos)
__global__ __launch_bounds__(256) void k_loss(const float* __restrict__ scores,
                                              float* __restrict__ out) {
    __shared__ float red[256];
    float s = 0.f;
    for (int i = threadIdx.x; i < BATCH; i += 256) {
        float x = scores[i * 2 + 1] - scores[i * 2 + 0];
        s += fmaxf(x, 0.f) + log1pf(expf(-fabsf(x)));
    }
    red[threadIdx.x] = s;
    __syncthreads();
    for (int w = 128; w > 0; w >>= 1) {
        if (threadIdx.x < w) red[threadIdx.x] += red[threadIdx.x + w];
        __syncthreads();
    }
    if (threadIdx.x == 0) out[0] = red[0] / (float)BATCH;
}

extern "C" void kernel_launch(void* const* d_in, const int* in_sizes, int n_in,
                              void* d_out, int out_size, void* d_ws, size_t ws_size,
                              hipStream_t stream) {
    const float* users_feature   = (const float*)d_in[0];
    const float* bundles_feature = (const float*)d_in[1];
    const float* items_feature   = (const float*)d_in[2];
    const float* cw1 = (const float*)d_in[3];
    const float* cb1 = (const float*)d_in[4];
    const float* cw2 = (const float*)d_in[5];
    const float* cb2 = (const float*)d_in[6];
    const float* sw1 = (const float*)d_in[7];
    const float* sb1 = (const float*)d_in[8];
    const float* sw2 = (const float*)d_in[9];
    const float* sb2 = (const float*)d_in[10];
    const float* ub_val = (const float*)d_in[11];
    const float* ui_val = (const float*)d_in[12];
    const float* bi_val = (const float*)d_in[13];
    const int* users   = (const int*)d_in[14];
    const int* bundles = (const int*)d_in[15];
    const int* ub_row = (const int*)d_in[16];
    const int* ub_col = (const int*)d_in[17];
    const int* ui_row = (const int*)d_in[18];
    const int* ui_col = (const int*)d_in[19];
    const int* bi_row = (const int*)d_in[20];
    const int* bi_col = (const int*)d_in[21];
    const int* bundle_items = (const int*)d_in[22];
    const int E_UB = in_sizes[11], E_UI = in_sizes[12], E_BI = in_sizes[13];
    const int E_TOT = E_UB + E_UI + E_BI;

    // workspace layout (4-byte elements), ~154 MB total.
    // cv_s (int2) must be 8B-aligned: all preceding sizes kept even.
    float* ws = (float*)d_ws;
    size_t off = 0;
    float* acc    = ws + off; off += (size_t)N_TOT * D;   // combined reps, 87 MB
    float* y1buf  = ws + off; off += (size_t)N_UI * D;    // per-graph temp, 38.4 MB
    float* scores = ws + off; off += (size_t)BATCH * NCAND;
    int*   cnt    = (int*)(ws + off); off += N_TOT;
    int*   rstart = (int*)(ws + off); off += N_TOT + 2;   // +2 keeps 8B alignment
    int*   cursor = (int*)(ws + off); off += N_TOT;
    int*   bsum   = (int*)(ws + off); off += 512;
    int2*  cv_s   = (int2*)(ws + off); off += (size_t)E_TOT * 2;  // packed (col,val)
    if (ws_size < off * sizeof(float)) return;  // fail loudly (wrong answer)

    // ---- fused CSR build (once, combined 340K-node space) ----
    hipMemsetAsync(cnt, 0, (size_t)N_TOT * sizeof(int), stream);
    k_hist3<<<(E_TOT + 255) / 256, 256, 0, stream>>>(ub_row, ui_row, bi_row,
                                                     E_UB, E_UI, E_BI, cnt);
    int nb = (N_TOT + SCAN_TILE - 1) / SCAN_TILE;   // 333
    k_scan1<<<nb, 256, 0, stream>>>(cnt, N_TOT, bsum);
    k_scan2<<<1, 256, 0, stream>>>(bsum, nb, rstart + N_TOT);
    k_scan3<<<nb, 256, 0, stream>>>(cnt, N_TOT, bsum, rstart, cursor);
    k_scatter3<<<(E_TOT + 255) / 256, 256, 0, stream>>>(
        ub_row, ub_col, ub_val, ui_row, ui_col, ui_val, bi_row, bi_col, bi_val,
        E_UB, E_UI, E_BI, cursor, cv_s);

    // ---- per-graph propagation (rs offsets index the combined edge array) --
    auto propagate = [&](int row_off, int n, const float* fa, int na,
                         const float* fb) {
        const int* rs = rstart + row_off;
        float* accg = acc + (size_t)row_off * D;
        int sb = (n + 15) / 16;
        k_spmm_l1<<<sb, 256, 0, stream>>>(rs, cv_s, fa, fb, na, y1buf, n);
        k_spmm_l2<<<sb, 256, 0, stream>>>(rs, cv_s, y1buf, fa, fb, na, accg, n);
    };
    propagate(0,    N_UB, users_feature,   NU, bundles_feature);
    propagate(OFF1, N_UI, users_feature,   NU, items_feature);
    propagate(OFF2, N_BI, bundles_feature, NB, items_feature);

    k_score<<<BATCH * NCAND, 256, 0, stream>>>(
        users, bundles, bundle_items,
        acc, acc + (size_t)OFF1 * D, acc + (size_t)OFF2 * D,
        cw1, cb1, cw2, cb2, sw1, sb1, sw2, sb2, scores);

    k_loss<<<1, 256, 0, stream>>>(scores, (float*)d_out);
}

// Round 11
// 641.775 us; speedup vs baseline: 1.3129x; 1.2062x over previous
//
#include <hip/hip_runtime.h>
#include <math.h>

// Problem constants (from reference)
constexpr int D = 64;
constexpr int NU = 50000, NB = 20000, NI = 100000;
constexpr int BATCH = 2048, NCAND = 2, MAXDEG = 50, CORE_K = 3;
constexpr int PAD_IDX = NI;
constexpr int N_UB = NU + NB, N_UI = NU + NI, N_BI = NB + NI;
constexpr int N_TOT = N_UB + N_UI + N_BI;   // 340000 combined node space
constexpr int OFF1 = N_UB;                  // UI node base
constexpr int OFF2 = N_UB + N_UI;           // BI node base
constexpr int SCAN_TILE = 1024;             // elems per scan block (256 thr x 4)

__device__ __forceinline__ float wave_sum64(float v) {
#pragma unroll
    for (int off = 32; off > 0; off >>= 1) v += __shfl_down(v, off);
    return v;  // valid in lane 0
}

// ---- bf16 via raw bit ops (no API surface; RNE pack, <<16 unpack) ----
__device__ __forceinline__ float bflo(unsigned u) { return __uint_as_float(u << 16); }
__device__ __forceinline__ float bfhi(unsigned u) { return __uint_as_float(u & 0xFFFF0000u); }
__device__ __forceinline__ unsigned short f2bf(float f) {
    unsigned u = __float_as_uint(f);
    u += 0x7FFF + ((u >> 16) & 1);      // round-nearest-even
    return (unsigned short)(u >> 16);
}
__device__ __forceinline__ unsigned pack2(float a, float b) {
    return (unsigned)f2bf(a) | ((unsigned)f2bf(b) << 16);
}
__device__ __forceinline__ float bf1(const unsigned short* p) {
    return __uint_as_float(((unsigned)*p) << 16);
}

// ---------------- fused CSR build over combined node space ----------------

__global__ void k_hist3(const int* __restrict__ r0, const int* __restrict__ r1,
                        const int* __restrict__ r2, int e0, int e1, int e2,
                        int* __restrict__ cnt) {
    int i = blockIdx.x * blockDim.x + threadIdx.x;
    if (i >= e0 + e1 + e2) return;
    int r;
    if (i < e0) r = r0[i];
    else if (i < e0 + e1) r = r1[i - e0] + OFF1;
    else r = r2[i - e0 - e1] + OFF2;
    atomicAdd(&cnt[r], 1);
}

// per-block partial sums of cnt tiles (tile = 1024, thread t owns 4 contiguous)
__global__ __launch_bounds__(256) void k_scan1(const int* __restrict__ cnt, int N,
                                               int* __restrict__ bsum) {
    __shared__ int red[256];
    int base = blockIdx.x * SCAN_TILE + threadIdx.x * 4;
    int s = 0;
#pragma unroll
    for (int k = 0; k < 4; ++k) { int i = base + k; if (i < N) s += cnt[i]; }
    red[threadIdx.x] = s;
    __syncthreads();
    for (int w = 128; w > 0; w >>= 1) {
        if (threadIdx.x < w) red[threadIdx.x] += red[threadIdx.x + w];
        __syncthreads();
    }
    if (threadIdx.x == 0) bsum[blockIdx.x] = red[0];
}

// single-block parallel exclusive scan of block sums (nb <= 512), double-barrier
// Hillis-Steele (proven R9). Also writes rs[N] = total.
__global__ __launch_bounds__(256) void k_scan2(int* __restrict__ bsum, int nb,
                                               int* __restrict__ rs_total) {
    __shared__ int s[256];
    int t = threadIdx.x;
    int i0 = 2 * t, i1 = 2 * t + 1;
    int v0 = (i0 < nb) ? bsum[i0] : 0;
    int v1 = (i1 < nb) ? bsum[i1] : 0;
    int ts = v0 + v1;
    s[t] = ts;
    __syncthreads();
    for (int off = 1; off < 256; off <<= 1) {
        int add = (t >= off) ? s[t - off] : 0;
        __syncthreads();
        s[t] += add;
        __syncthreads();
    }
    int pre = s[t] - ts;   // exclusive prefix of this thread's pair
    if (i0 < nb) bsum[i0] = pre;
    if (i1 < nb) bsum[i1] = pre + v0;
    if (t == 255) *rs_total = s[255];   // == E_tot
}

// per-block exclusive scan of tile, + scanned block offset -> row_start & cursor
__global__ __launch_bounds__(256) void k_scan3(const int* __restrict__ cnt, int N,
                                               const int* __restrict__ bsum,
                                               int* __restrict__ rs,
                                               int* __restrict__ cursor) {
    __shared__ int s_ts[256];
    int t = threadIdx.x;
    int base = blockIdx.x * SCAN_TILE + t * 4;
    int v[4];
#pragma unroll
    for (int k = 0; k < 4; ++k) { int i = base + k; v[k] = (i < N) ? cnt[i] : 0; }
    int ts = v[0] + v[1] + v[2] + v[3];
    s_ts[t] = ts;
    __syncthreads();
    for (int off = 1; off < 256; off <<= 1) {
        int add = (t >= off) ? s_ts[t - off] : 0;
        __syncthreads();
        s_ts[t] += add;
        __syncthreads();
    }
    int pre = bsum[blockIdx.x] + (s_ts[t] - ts);
#pragma unroll
    for (int k = 0; k < 4; ++k) {
        int i = base + k;
        if (i < N) { rs[i] = pre; cursor[i] = pre; }
        pre += v[k];
    }
}

// scatter all three edge lists; (col,val) packed int2, PLAIN 8B store
// (R9: nontemporal regressed +70us). cols stored GRAPH-LOCAL.
__global__ void k_scatter3(const int* __restrict__ r0, const int* __restrict__ c0,
                           const float* __restrict__ v0,
                           const int* __restrict__ r1, const int* __restrict__ c1,
                           const float* __restrict__ v1,
                           const int* __restrict__ r2, const int* __restrict__ c2,
                           const float* __restrict__ v2,
                           int e0, int e1, int e2,
                           int* __restrict__ cursor,
                           int2* __restrict__ cv_s) {
    int i = blockIdx.x * blockDim.x + threadIdx.x;
    if (i >= e0 + e1 + e2) return;
    int r, c; float v;
    if (i < e0)            { r = r0[i];          c = c0[i];          v = v0[i]; }
    else if (i < e0 + e1)  { int k = i - e0;      r = r1[k] + OFF1;   c = c1[k]; v = v1[k]; }
    else                   { int k = i - e0 - e1; r = r2[k] + OFF2;   c = c2[k]; v = v2[k]; }
    int p = atomicAdd(&cursor[r], 1);
    cv_s[p] = make_int2(c, __float_as_int(v));
}

// ---------------- bf16 staging: xb = concat features per section ------------
// xb[row*64 + q] (bf16) for all 340K combined rows; gathered rows are 128B
// (2 lines) instead of 256B, and all three sections' source tables fit L2/L3.
__global__ __launch_bounds__(256) void k_cvt(const float* __restrict__ uf,
                                             const float* __restrict__ bf,
                                             const float* __restrict__ itf,
                                             unsigned short* __restrict__ xb) {
    size_t i = (size_t)blockIdx.x * 256 + threadIdx.x;   // 4-element group
    if (i >= (size_t)N_TOT * 16) return;
    int row = (int)(i >> 4);
    int q = ((int)i & 15) * 4;
    const float* src;
    if (row < OFF1) {
        int l = row;
        src = (l < NU) ? uf + (size_t)l * D : bf + (size_t)(l - NU) * D;
    } else if (row < OFF2) {
        int l = row - OFF1;
        src = (l < NU) ? uf + (size_t)l * D : itf + (size_t)(l - NU) * D;
    } else {
        int l = row - OFF2;
        src = (l < NB) ? bf + (size_t)l * D : itf + (size_t)(l - NB) * D;
    }
    float4 v = *(const float4*)(src + q);
    ushort4 o;
    o.x = f2bf(v.x); o.y = f2bf(v.y); o.z = f2bf(v.z); o.w = f2bf(v.w);
    *(ushort4*)(xb + (size_t)row * D + q) = o;
}

// ---------------- propagate: merged single-launch bf16 SpMM ----------------
// One kernel over all 340K combined rows (was 3 launches/layer). 8 lanes per
// row, 16B bf16x8 loads, 4-edge unroll. Section base for graph-local cols is
// derived from the row index — xb's concat layout makes fa/fb branching moot.

// layer 1: y1[r] = sum_j val[j] * xb[base + col[j]]
__global__ __launch_bounds__(256) void k_spmm_l1(
    const int* __restrict__ rs, const int2* __restrict__ cv,
    const unsigned short* __restrict__ xb, unsigned short* __restrict__ y1) {
    int r = blockIdx.x * 32 + (threadIdx.x >> 3);
    int t = threadIdx.x & 7;            // 8 bf16 features per lane
    if (r >= N_TOT) return;
    int base = (r < OFF1) ? 0 : ((r < OFF2) ? OFF1 : OFF2);
    int s = rs[r], e = rs[r + 1];
    float a[8];
#pragma unroll
    for (int k = 0; k < 8; ++k) a[k] = 0.f;
    int j = s;
    for (; j + 3 < e; j += 4) {
        int2 q[4]; uint4 u[4];
#pragma unroll
        for (int k = 0; k < 4; ++k) q[k] = cv[j + k];
#pragma unroll
        for (int k = 0; k < 4; ++k)
            u[k] = *(const uint4*)(xb + (((size_t)(base + q[k].x)) << 6) + t * 8);
#pragma unroll
        for (int k = 0; k < 4; ++k) {
            float v = __int_as_float(q[k].y);
            a[0] = fmaf(v, bflo(u[k].x), a[0]); a[1] = fmaf(v, bfhi(u[k].x), a[1]);
            a[2] = fmaf(v, bflo(u[k].y), a[2]); a[3] = fmaf(v, bfhi(u[k].y), a[3]);
            a[4] = fmaf(v, bflo(u[k].z), a[4]); a[5] = fmaf(v, bfhi(u[k].z), a[5]);
            a[6] = fmaf(v, bflo(u[k].w), a[6]); a[7] = fmaf(v, bfhi(u[k].w), a[7]);
        }
    }
    for (; j < e; ++j) {
        int2 q0 = cv[j];
        uint4 u0 = *(const uint4*)(xb + (((size_t)(base + q0.x)) << 6) + t * 8);
        float v = __int_as_float(q0.y);
        a[0] = fmaf(v, bflo(u0.x), a[0]); a[1] = fmaf(v, bfhi(u0.x), a[1]);
        a[2] = fmaf(v, bflo(u0.y), a[2]); a[3] = fmaf(v, bfhi(u0.y), a[3]);
        a[4] = fmaf(v, bflo(u0.z), a[4]); a[5] = fmaf(v, bfhi(u0.z), a[5]);
        a[6] = fmaf(v, bflo(u0.w), a[6]); a[7] = fmaf(v, bfhi(u0.w), a[7]);
    }
    uint4 o;
    o.x = pack2(a[0], a[1]); o.y = pack2(a[2], a[3]);
    o.z = pack2(a[4], a[5]); o.w = pack2(a[6], a[7]);
    *(uint4*)(y1 + ((size_t)r << 6) + t * 8) = o;
}

// layer 2 + mean: acc[r] = (xb[r] + y1[r] + sum_j val[j]*y1[base+col[j]]) / 3
__global__ __launch_bounds__(256) void k_spmm_l2(
    const int* __restrict__ rs, const int2* __restrict__ cv,
    const unsigned short* __restrict__ xb, const unsigned short* __restrict__ y1,
    unsigned short* __restrict__ acc) {
    int r = blockIdx.x * 32 + (threadIdx.x >> 3);
    int t = threadIdx.x & 7;
    if (r >= N_TOT) return;
    int base = (r < OFF1) ? 0 : ((r < OFF2) ? OFF1 : OFF2);
    int s = rs[r], e = rs[r + 1];
    float a[8];
#pragma unroll
    for (int k = 0; k < 8; ++k) a[k] = 0.f;
    int j = s;
    for (; j + 3 < e; j += 4) {
        int2 q[4]; uint4 u[4];
#pragma unroll
        for (int k = 0; k < 4; ++k) q[k] = cv[j + k];
#pragma unroll
        for (int k = 0; k < 4; ++k)
            u[k] = *(const uint4*)(y1 + (((size_t)(base + q[k].x)) << 6) + t * 8);
#pragma unroll
        for (int k = 0; k < 4; ++k) {
            float v = __int_as_float(q[k].y);
            a[0] = fmaf(v, bflo(u[k].x), a[0]); a[1] = fmaf(v, bfhi(u[k].x), a[1]);
            a[2] = fmaf(v, bflo(u[k].y), a[2]); a[3] = fmaf(v, bfhi(u[k].y), a[3]);
            a[4] = fmaf(v, bflo(u[k].z), a[4]); a[5] = fmaf(v, bfhi(u[k].z), a[5]);
            a[6] = fmaf(v, bflo(u[k].w), a[6]); a[7] = fmaf(v, bfhi(u[k].w), a[7]);
        }
    }
    for (; j < e; ++j) {
        int2 q0 = cv[j];
        uint4 u0 = *(const uint4*)(y1 + (((size_t)(base + q0.x)) << 6) + t * 8);
        float v = __int_as_float(q0.y);
        a[0] = fmaf(v, bflo(u0.x), a[0]); a[1] = fmaf(v, bfhi(u0.x), a[1]);
        a[2] = fmaf(v, bflo(u0.y), a[2]); a[3] = fmaf(v, bfhi(u0.y), a[3]);
        a[4] = fmaf(v, bflo(u0.z), a[4]); a[5] = fmaf(v, bfhi(u0.z), a[5]);
        a[6] = fmaf(v, bflo(u0.w), a[6]); a[7] = fmaf(v, bfhi(u0.w), a[7]);
    }
    uint4 fx = *(const uint4*)(xb + ((size_t)r << 6) + t * 8);
    uint4 yx = *(const uint4*)(y1 + ((size_t)r << 6) + t * 8);
    constexpr float k3 = 1.0f / 3.0f;
    float o[8];
    o[0] = (bflo(fx.x) + bflo(yx.x) + a[0]) * k3;
    o[1] = (bfhi(fx.x) + bfhi(yx.x) + a[1]) * k3;
    o[2] = (bflo(fx.y) + bflo(yx.y) + a[2]) * k3;
    o[3] = (bfhi(fx.y) + bfhi(yx.y) + a[3]) * k3;
    o[4] = (bflo(fx.z) + bflo(yx.z) + a[4]) * k3;
    o[5] = (bfhi(fx.z) + bfhi(yx.z) + a[5]) * k3;
    o[6] = (bflo(fx.w) + bflo(yx.w) + a[6]) * k3;
    o[7] = (bfhi(fx.w) + bfhi(yx.w) + a[7]) * k3;
    uint4 w;
    w.x = pack2(o[0], o[1]); w.y = pack2(o[2], o[3]);
    w.z = pack2(o[4], o[5]); w.w = pack2(o[6], o[7]);
    *(uint4*)(acc + ((size_t)r << 6) + t * 8) = w;
}

// ---------------- scoring (reps now bf16) ----------------
// 256-thread block per candidate pair. Same proven phase structure as R6-R10;
// only the global loads of m_* changed to bf16 (uint2 = 4 bf16 per lane).
__global__ __launch_bounds__(256) void k_score(
    const int* __restrict__ users, const int* __restrict__ bundles,
    const int* __restrict__ bundle_items,
    const unsigned short* __restrict__ m_ub,
    const unsigned short* __restrict__ m_ui,
    const unsigned short* __restrict__ m_bi,
    const float* __restrict__ cw1, const float* __restrict__ cb1,
    const float* __restrict__ cw2, const float* __restrict__ cb2,
    const float* __restrict__ sw1, const float* __restrict__ sb1,
    const float* __restrict__ sw2, const float* __restrict__ sb2,
    float* __restrict__ scores) {
    const int n = blockIdx.x;
    const int t = threadIdx.x;      // 0..255
    const int ln = t & 63;          // lane within wave
    const int wv = t >> 6;          // wave 0..3
    const int g16 = t >> 4;         // group 0..15
    const int l16 = t & 15;         // lane within group
    const int u = users[n >> 1];
    const int b = bundles[n];

    __shared__ float s_items[MAXDEG][D];   // items_ui stash (12.8 KB)
    __shared__ float s_r[2][MAXDEG];
    __shared__ float s_pi[MAXDEG];
    __shared__ int   s_idx[MAXDEG];
    __shared__ int   s_top_i[CORE_K];
    __shared__ float s_top_p[CORE_K];
    __shared__ float s_syn[2 * D];
    __shared__ float s_part[4][D];
    __shared__ float s_h1[D];

    if (t < MAXDEG) s_idx[t] = bundle_items[(size_t)b * MAXDEG + t];
    __syncthreads();

    // this thread's 4-feature segment of the u / b rows (bf16 -> f32)
    uint2 uu = *(const uint2*)(m_ui + ((size_t)u << 6) + l16 * 4);
    uint2 bb = *(const uint2*)(m_bi + ((size_t)b << 6) + l16 * 4);
    const float u0 = bflo(uu.x), u1 = bfhi(uu.x), u2 = bflo(uu.y), u3 = bfhi(uu.y);
    const float b0 = bflo(bb.x), b1 = bfhi(bb.x), b2 = bflo(bb.y), b3 = bfhi(bb.y);

    // --- P1: 50 dual dot products, 16 items in flight (16 lanes x 4 bf16) ---
    for (int m = g16; m < MAXDEG; m += 16) {
        int it = s_idx[m];
        float i0 = 0.f, i1 = 0.f, i2 = 0.f, i3 = 0.f;
        float j0 = 0.f, j1 = 0.f, j2 = 0.f, j3 = 0.f;
        if (it != PAD_IDX) {
            uint2 iu = *(const uint2*)(m_ui + ((size_t)(NU + it) << 6) + l16 * 4);
            uint2 ib = *(const uint2*)(m_bi + ((size_t)(NB + it) << 6) + l16 * 4);
            i0 = bflo(iu.x); i1 = bfhi(iu.x); i2 = bflo(iu.y); i3 = bfhi(iu.y);
            j0 = bflo(ib.x); j1 = bfhi(ib.x); j2 = bflo(ib.y); j3 = bfhi(ib.y);
        }
        *(float4*)(&s_items[m][l16 * 4]) = make_float4(i0, i1, i2, i3);
        float pu = u0 * i0 + u1 * i1 + u2 * i2 + u3 * i3;
        float pb = b0 * j0 + b1 * j1 + b2 * j2 + b3 * j3;
#pragma unroll
        for (int off = 8; off > 0; off >>= 1) {
            pu += __shfl_down(pu, off, 16);
            pb += __shfl_down(pb, off, 16);
        }
        if (l16 == 0) { s_r[0][m] = pu; s_r[1][m] = pb; }
    }
    __syncthreads();

    // --- P2: core MLP (2->32->1) per item, threads 0..49; logits -> s_pi ---
    if (t < MAXDEG) {
        float rU = s_r[0][t], rB = s_r[1][t];
        float acc = cb2[0];
#pragma unroll
        for (int j = 0; j < 32; ++j) {
            float h = fmaf(rU, cw1[j], fmaf(rB, cw1[32 + j], cb1[j]));
            h = fmaxf(h, 0.f);
            acc = fmaf(h, cw2[j], acc);
        }
        s_pi[t] = (s_idx[t] != PAD_IDX) ? acc : -INFINITY;
    }
    __syncthreads();

    // --- P3 (thread 0, serial; R3-proven): softmax + top-3 ---
    if (t == 0) {
        float mx = -INFINITY;
        for (int m = 0; m < MAXDEG; ++m) mx = fmaxf(mx, s_pi[m]);
        float sm = 0.f;
        for (int m = 0; m < MAXDEG; ++m) {
            float e = expf(s_pi[m] - mx);
            s_pi[m] = e;
            sm += e;
        }
        float inv_sm = 1.f / sm;
        for (int m = 0; m < MAXDEG; ++m) s_pi[m] *= inv_sm;
        bool used[MAXDEG];
        for (int m = 0; m < MAXDEG; ++m) used[m] = false;
        float tsum = 0.f;
        for (int k = 0; k < CORE_K; ++k) {
            float best = -1.f; int bidx = 0;
            for (int m = 0; m < MAXDEG; ++m)
                if (!used[m] && s_pi[m] > best) { best = s_pi[m]; bidx = m; }
            used[bidx] = true;
            s_top_i[k] = bidx;
            s_top_p[k] = best;
            tsum += best;
        }
        float inv = 1.f / (tsum + 1e-10f);
        for (int k = 0; k < CORE_K; ++k) s_top_p[k] *= inv;
    }
    __syncthreads();

    // --- P4 (wave 0): h_core / h_fringe per feature dim ln ---
    if (wv == 0) {
        int ti0 = s_top_i[0], ti1 = s_top_i[1], ti2 = s_top_i[2];
        float hcore = s_items[ti0][ln] * s_top_p[0]
                    + s_items[ti1][ln] * s_top_p[1]
                    + s_items[ti2][ln] * s_top_p[2];
        float fsum = 0.f; int fcnt = 0;
        for (int m = 0; m < MAXDEG; ++m) {
            bool core = (m == ti0) | (m == ti1) | (m == ti2);
            if ((s_idx[m] != PAD_IDX) && !core) { fsum += s_items[m][ln]; fcnt++; }
        }
        float hfr = fsum / fmaxf((float)fcnt, 1.f);
        s_syn[ln] = hcore;
        s_syn[D + ln] = hfr;
    }
    __syncthreads();

    // --- P5: synergy MLP (128->64->64) split across 4 waves ---
    float h1p = 0.f;
    for (int k = 0; k < 32; ++k) {
        int kk = wv * 32 + k;
        h1p = fmaf(s_syn[kk], sw1[kk * D + ln], h1p);
    }
    s_part[wv][ln] = h1p;
    __syncthreads();
    if (t < D) {
        float h1 = sb1[t] + s_part[0][t] + s_part[1][t] + s_part[2][t] + s_part[3][t];
        s_h1[t] = fmaxf(h1, 0.f);
    }
    __syncthreads();
    float php = 0.f;
    for (int k = 0; k < 16; ++k) {
        int kk = wv * 16 + k;
        php = fmaf(s_h1[kk], sw2[kk * D + ln], php);
    }
    s_part[wv][ln] = php;
    __syncthreads();

    // --- P6 (wave 0): final score ---
    if (wv == 0) {
        float phi = sb2[ln] + s_part[0][ln] + s_part[1][ln] + s_part[2][ln] + s_part[3][ln];
        float hat = s_syn[ln] + phi;     // hcore + phi
        float uui = bf1(m_ui + ((size_t)u << 6) + ln);
        float ubu = bf1(m_ub + ((size_t)u << 6) + ln);
        float ubb = bf1(m_ub + ((size_t)(NU + b) << 6) + ln);
        float part = wave_sum64(uui * ubb + ubu * hat);
        if (ln == 0) scores[n] = part;
    }
}

// mean over batch of softplus(neg - pos)
__global__ __launch_bounds__(256) void k_loss(const float* __restrict__ scores,
                                              float* __restrict__ out) {
    __shared__ float red[256];
    float s = 0.f;
    for (int i = threadIdx.x; i < BATCH; i += 256) {
        float x = scores[i * 2 + 1] - scores[i * 2 + 0];
        s += fmaxf(x, 0.f) + log1pf(expf(-fabsf(x)));
    }
    red[threadIdx.x] = s;
    __syncthreads();
    for (int w = 128; w > 0; w >>= 1) {
        if (threadIdx.x < w) red[threadIdx.x] += red[threadIdx.x + w];
        __syncthreads();
    }
    if (threadIdx.x == 0) out[0] = red[0] / (float)BATCH;
}

extern "C" void kernel_launch(void* const* d_in, const int* in_sizes, int n_in,
                              void* d_out, int out_size, void* d_ws, size_t ws_size,
                              hipStream_t stream) {
    const float* users_feature   = (const float*)d_in[0];
    const float* bundles_feature = (const float*)d_in[1];
    const float* items_feature   = (const float*)d_in[2];
    const float* cw1 = (const float*)d_in[3];
    const float* cb1 = (const float*)d_in[4];
    const float* cw2 = (const float*)d_in[5];
    const float* cb2 = (const float*)d_in[6];
    const float* sw1 = (const float*)d_in[7];
    const float* sb1 = (const float*)d_in[8];
    const float* sw2 = (const float*)d_in[9];
    const float* sb2 = (const float*)d_in[10];
    const float* ub_val = (const float*)d_in[11];
    const float* ui_val = (const float*)d_in[12];
    const float* bi_val = (const float*)d_in[13];
    const int* users   = (const int*)d_in[14];
    const int* bundles = (const int*)d_in[15];
    const int* ub_row = (const int*)d_in[16];
    const int* ub_col = (const int*)d_in[17];
    const int* ui_row = (const int*)d_in[18];
    const int* ui_col = (const int*)d_in[19];
    const int* bi_row = (const int*)d_in[20];
    const int* bi_col = (const int*)d_in[21];
    const int* bundle_items = (const int*)d_in[22];
    const int E_UB = in_sizes[11], E_UI = in_sizes[12], E_BI = in_sizes[13];
    const int E_TOT = E_UB + E_UI + E_BI;

    // workspace layout (4-byte units), ~159 MB total (R1 proved >=164 MB ok).
    // bf16 arrays are N_TOT*64 ushorts = N_TOT*32 floats each.
    float* ws = (float*)d_ws;
    size_t off = 0;
    unsigned short* accb = (unsigned short*)(ws + off); off += (size_t)N_TOT * 32;
    unsigned short* xb   = (unsigned short*)(ws + off); off += (size_t)N_TOT * 32;
    unsigned short* y1b  = (unsigned short*)(ws + off); off += (size_t)N_TOT * 32;
    float* scores = ws + off; off += (size_t)BATCH * NCAND;
    int*   cnt    = (int*)(ws + off); off += N_TOT;
    int*   rstart = (int*)(ws + off); off += N_TOT + 2;   // +2 keeps 8B alignment
    int*   cursor = (int*)(ws + off); off += N_TOT;
    int*   bsum   = (int*)(ws + off); off += 512;
    int2*  cv_s   = (int2*)(ws + off); off += (size_t)E_TOT * 2;  // packed (col,val)
    if (ws_size < off * sizeof(float)) return;  // fail loudly (wrong answer)

    // ---- fused CSR build (once, combined 340K-node space) ----
    hipMemsetAsync(cnt, 0, (size_t)N_TOT * sizeof(int), stream);
    k_hist3<<<(E_TOT + 255) / 256, 256, 0, stream>>>(ub_row, ui_row, bi_row,
                                                     E_UB, E_UI, E_BI, cnt);
    int nb = (N_TOT + SCAN_TILE - 1) / SCAN_TILE;   // 333
    k_scan1<<<nb, 256, 0, stream>>>(cnt, N_TOT, bsum);
    k_scan2<<<1, 256, 0, stream>>>(bsum, nb, rstart + N_TOT);
    k_scan3<<<nb, 256, 0, stream>>>(cnt, N_TOT, bsum, rstart, cursor);
    k_scatter3<<<(E_TOT + 255) / 256, 256, 0, stream>>>(
        ub_row, ub_col, ub_val, ui_row, ui_col, ui_val, bi_row, bi_col, bi_val,
        E_UB, E_UI, E_BI, cursor, cv_s);

    // ---- bf16 staging + merged 2-layer propagation over all 340K rows ----
    k_cvt<<<(int)(((size_t)N_TOT * 16 + 255) / 256), 256, 0, stream>>>(
        users_feature, bundles_feature, items_feature, xb);
    int sb = (N_TOT + 31) / 32;
    k_spmm_l1<<<sb, 256, 0, stream>>>(rstart, cv_s, xb, y1b);
    k_spmm_l2<<<sb, 256, 0, stream>>>(rstart, cv_s, xb, y1b, accb);

    k_score<<<BATCH * NCAND, 256, 0, stream>>>(
        users, bundles, bundle_items,
        accb, accb + (size_t)OFF1 * D, accb + (size_t)OFF2 * D,
        cw1, cb1, cw2, cb2, sw1, sb1, sw2, sb2, scores);

    k_loss<<<1, 256, 0, stream>>>(scores, (float*)d_out);
}